// Round 8
// baseline (6786.341 us; speedup 1.0000x reference)
//
#include <hip/hip_runtime.h>
#include <math.h>

#define N 1024
#define NN (N*N)

// ======================= init =======================
__global__ void init_kernel(double* scores) {
  int t = threadIdx.x;
  if (t < 16) scores[t] = 0.0;
}

// ======================= copy x -> LU workspace =======================
__global__ __launch_bounds__(256) void copy_kernel(const float4* __restrict__ src,
                                                   float4* __restrict__ dst) {
  int i = blockIdx.x * 256 + threadIdx.x;   // grid sized exactly: 16M floats / 4
  dst[i] = src[i];
}

// ======================= LU panel (width 64): 256 thr x 4 rows, quad-outer ====
// History: 512-thread blocks spilled the row set at BOTH launch_bounds (r5:
// VGPR=108, r7: VGPR=84, 6.1MB scratch HBM each); the only clean register panel
// was round-2's 256-thread / 4-row-group shape. This kernel keeps that exact
// shape and extends quads 8->16 for width 64: 64 named float4 (256 VGPR data)
// + quad-outer U-read (4 VGPR transient, no staged U quads) ~= 290 peak, under
// the 512-VGPR cap of a 4-wave block (no spill through 450 per HW notes).
// Rows tid+{0,256,512,768}. Virtual pivoting via Vv/Pv; prow broadcast; fused
// next-col scan; 2 barriers/step; consolidating writeback; rowsrc emitted.
__global__ __launch_bounds__(256, 1) void panel_kernel(float* __restrict__ lu,
                                                       unsigned short* __restrict__ rowsrc,
                                                       double* __restrict__ scores,
                                                       int c0) {
  __shared__ __align__(16) float prow[64];   // pivot row broadcast buffer
  __shared__ float ujjS[64];
  __shared__ float redv[2][4];               // parity-buffered cross-wave reduce
  __shared__ int   redk[2][4];
  __shared__ int Vv[1024];                   // virtual -> physical (rel c0)
  __shared__ int Pv[1024];                   // physical -> virtual
  const int m = blockIdx.x;
  float* A = lu + (size_t)m * NN;
  const int R = N - c0;
  const int tid = threadIdx.x;

  const float4 z4 = make_float4(0.f, 0.f, 0.f, 0.f);
  float4 r0_0=z4, r0_1=z4, r0_2=z4, r0_3=z4, r0_4=z4, r0_5=z4, r0_6=z4, r0_7=z4;
  float4 r0_8=z4, r0_9=z4, r0_10=z4, r0_11=z4, r0_12=z4, r0_13=z4, r0_14=z4, r0_15=z4;
  float4 r1_0=z4, r1_1=z4, r1_2=z4, r1_3=z4, r1_4=z4, r1_5=z4, r1_6=z4, r1_7=z4;
  float4 r1_8=z4, r1_9=z4, r1_10=z4, r1_11=z4, r1_12=z4, r1_13=z4, r1_14=z4, r1_15=z4;
  float4 r2_0=z4, r2_1=z4, r2_2=z4, r2_3=z4, r2_4=z4, r2_5=z4, r2_6=z4, r2_7=z4;
  float4 r2_8=z4, r2_9=z4, r2_10=z4, r2_11=z4, r2_12=z4, r2_13=z4, r2_14=z4, r2_15=z4;
  float4 r3_0=z4, r3_1=z4, r3_2=z4, r3_3=z4, r3_4=z4, r3_5=z4, r3_6=z4, r3_7=z4;
  float4 r3_8=z4, r3_9=z4, r3_10=z4, r3_11=z4, r3_12=z4, r3_13=z4, r3_14=z4, r3_15=z4;

  const bool ld0 = (tid       < R);
  const bool ld1 = (tid + 256 < R);
  const bool ld2 = (tid + 512 < R);
  const bool ld3 = (tid + 768 < R);
  bool act0 = ld0, act1 = ld1, act2 = ld2, act3 = ld3;

#define LOADK(K) \
  if (ld##K) { \
    const float* src_ = A + (size_t)(c0 + tid + (K << 8)) * N + c0; \
    r##K##_0  = *(const float4*)(src_ +  0); \
    r##K##_1  = *(const float4*)(src_ +  4); \
    r##K##_2  = *(const float4*)(src_ +  8); \
    r##K##_3  = *(const float4*)(src_ + 12); \
    r##K##_4  = *(const float4*)(src_ + 16); \
    r##K##_5  = *(const float4*)(src_ + 20); \
    r##K##_6  = *(const float4*)(src_ + 24); \
    r##K##_7  = *(const float4*)(src_ + 28); \
    r##K##_8  = *(const float4*)(src_ + 32); \
    r##K##_9  = *(const float4*)(src_ + 36); \
    r##K##_10 = *(const float4*)(src_ + 40); \
    r##K##_11 = *(const float4*)(src_ + 44); \
    r##K##_12 = *(const float4*)(src_ + 48); \
    r##K##_13 = *(const float4*)(src_ + 52); \
    r##K##_14 = *(const float4*)(src_ + 56); \
    r##K##_15 = *(const float4*)(src_ + 60); \
  }
  LOADK(0) LOADK(1) LOADK(2) LOADK(3)
#undef LOADK

  for (int i = tid; i < R; i += 256) { Vv[i] = i; Pv[i] = i; }

  // ---- prescan: pivot for column 0 ----
  {
    float bval = -1.0f; int brow = 0x7fffffff;
    if (act0) { float v = fabsf(r0_0.x); if (v > bval || (v == bval && tid       < brow)) { bval = v; brow = tid;       } }
    if (act1) { float v = fabsf(r1_0.x); if (v > bval || (v == bval && tid + 256 < brow)) { bval = v; brow = tid + 256; } }
    if (act2) { float v = fabsf(r2_0.x); if (v > bval || (v == bval && tid + 512 < brow)) { bval = v; brow = tid + 512; } }
    if (act3) { float v = fabsf(r3_0.x); if (v > bval || (v == bval && tid + 768 < brow)) { bval = v; brow = tid + 768; } }
    #pragma unroll
    for (int mask = 32; mask; mask >>= 1) {
      float ov = __shfl_xor(bval, mask);
      int   orr = __shfl_xor(brow, mask);
      if (ov > bval || (ov == bval && orr < brow)) { bval = ov; brow = orr; }
    }
    if ((tid & 63) == 0) { redv[0][tid >> 6] = bval; redk[0][tid >> 6] = brow; }
  }
  __syncthreads();   // redv[0] + Vv/Pv init visible

  #pragma unroll 1
  for (int j = 0; j < 64; ++j) {
    // ---- combine 4-wave partials -> physical pivot row pcur (redundant, all) ----
    int pcur;
    {
      const int pb = j & 1;
      float bv = redv[pb][0]; int bk = redk[pb][0];
      float v1 = redv[pb][1]; int k1 = redk[pb][1];
      float v2 = redv[pb][2]; int k2 = redk[pb][2];
      float v3 = redv[pb][3]; int k3 = redk[pb][3];
      if (v1 > bv || (v1 == bv && k1 < bk)) { bv = v1; bk = k1; }
      if (v2 > bv || (v2 == bv && k2 < bk)) { bv = v2; bk = k2; }
      if (v3 > bv || (v3 == bv && k3 < bk)) { bv = v3; bk = k3; }
      pcur = bk;
    }
    // ---- owner publishes pivot row from registers; retires it ----
    if (tid == (pcur & 255)) {
      const int kk = pcur >> 8;
      float4* pd = (float4*)prow;
#define PUBQ(Q) { \
      float4 v = r0_##Q; \
      if (kk == 1) v = r1_##Q; \
      if (kk == 2) v = r2_##Q; \
      if (kk == 3) v = r3_##Q; \
      pd[Q] = v; }
      PUBQ(0) PUBQ(1) PUBQ(2) PUBQ(3) PUBQ(4) PUBQ(5) PUBQ(6) PUBQ(7)
      PUBQ(8) PUBQ(9) PUBQ(10) PUBQ(11) PUBQ(12) PUBQ(13) PUBQ(14) PUBQ(15)
#undef PUBQ
      if (kk == 0) act0 = false;
      else if (kk == 1) act1 = false;
      else if (kk == 2) act2 = false;
      else act3 = false;
    }
    // ---- thread 0: maintain virtual<->physical permutation ----
    if (tid == 0) {
      int b  = Pv[pcur];                // virtual index of pivot (>= j)
      int pa = Vv[j];
      Vv[j] = pcur; Vv[b] = pa;
      Pv[pcur] = j; Pv[pa] = b;
    }
    __syncthreads();   // B1: prow visible

    const float ujj = prow[j];
    if (tid == 0) ujjS[j] = ujj;
    const float rujj = 1.0f / ujj;
    const int qj = j >> 2, ej = j & 3;
    const int jn = j + 1;
    const int qn = (j < 63) ? (jn >> 2) : -1, en = jn & 3;

    // ---- quad-outer update: per quad, 1 LDS broadcast read, all 4 rows ----
    float l0 = 0.0f, nv0 = 0.0f, l1 = 0.0f, nv1 = 0.0f;
    float l2 = 0.0f, nv2 = 0.0f, l3 = 0.0f, nv3 = 0.0f;
#define ROWQ(K, Q, LK, NVK) { \
      float4 v = r##K##_##Q; \
      if (Q == qj) { \
        float aj = (ej == 0) ? v.x : (ej == 1) ? v.y : (ej == 2) ? v.z : v.w; \
        LK = aj * rujj; \
        if (ej == 0)      { v.x = LK; v.y -= LK * uq.y; v.z -= LK * uq.z; v.w -= LK * uq.w; } \
        else if (ej == 1) { v.y = LK; v.z -= LK * uq.z; v.w -= LK * uq.w; } \
        else if (ej == 2) { v.z = LK; v.w -= LK * uq.w; } \
        else              { v.w = LK; } \
      } else { \
        v.x -= LK * uq.x; v.y -= LK * uq.y; v.z -= LK * uq.z; v.w -= LK * uq.w; \
      } \
      if (Q == qn) NVK = (en == 0) ? v.x : (en == 1) ? v.y : (en == 2) ? v.z : v.w; \
      r##K##_##Q = v; \
    }
#define QS2(Q) { \
      if (Q >= qj) { \
        const float4 uq = *(const float4*)&prow[4 * Q]; \
        if (act0) ROWQ(0, Q, l0, nv0) \
        if (act1) ROWQ(1, Q, l1, nv1) \
        if (act2) ROWQ(2, Q, l2, nv2) \
        if (act3) ROWQ(3, Q, l3, nv3) \
      } \
    }
    QS2(0) QS2(1) QS2(2) QS2(3) QS2(4) QS2(5) QS2(6) QS2(7)
    QS2(8) QS2(9) QS2(10) QS2(11) QS2(12) QS2(13) QS2(14) QS2(15)
#undef QS2
#undef ROWQ

    if (j < 63) {
      float bval = -1.0f; int brow = 0x7fffffff;
      if (act0) { float av = fabsf(nv0); if (av > bval || (av == bval && tid       < brow)) { bval = av; brow = tid;       } }
      if (act1) { float av = fabsf(nv1); if (av > bval || (av == bval && tid + 256 < brow)) { bval = av; brow = tid + 256; } }
      if (act2) { float av = fabsf(nv2); if (av > bval || (av == bval && tid + 512 < brow)) { bval = av; brow = tid + 512; } }
      if (act3) { float av = fabsf(nv3); if (av > bval || (av == bval && tid + 768 < brow)) { bval = av; brow = tid + 768; } }
      #pragma unroll
      for (int mask = 32; mask; mask >>= 1) {
        float ov = __shfl_xor(bval, mask);
        int   orr = __shfl_xor(brow, mask);
        if (ov > bval || (ov == bval && orr < brow)) { bval = ov; brow = orr; }
      }
      if ((tid & 63) == 0) { redv[jn & 1][tid >> 6] = bval; redk[jn & 1][tid >> 6] = brow; }
    }
    __syncthreads();   // B2: updates done reading prow; redv visible for next step
  }

  // ---- CONSOLIDATED writeback: phys slot p's content -> physical row c0+Pv[p] ----
#define STOREK(K) \
  if (ld##K) { \
    const int p_ = tid + (K << 8); \
    float* dst_ = A + (size_t)(c0 + Pv[p_]) * N + c0; \
    *(float4*)(dst_ +  0) = r##K##_0;  *(float4*)(dst_ +  4) = r##K##_1; \
    *(float4*)(dst_ +  8) = r##K##_2;  *(float4*)(dst_ + 12) = r##K##_3; \
    *(float4*)(dst_ + 16) = r##K##_4;  *(float4*)(dst_ + 20) = r##K##_5; \
    *(float4*)(dst_ + 24) = r##K##_6;  *(float4*)(dst_ + 28) = r##K##_7; \
    *(float4*)(dst_ + 32) = r##K##_8;  *(float4*)(dst_ + 36) = r##K##_9; \
    *(float4*)(dst_ + 40) = r##K##_10; *(float4*)(dst_ + 44) = r##K##_11; \
    *(float4*)(dst_ + 48) = r##K##_12; *(float4*)(dst_ + 52) = r##K##_13; \
    *(float4*)(dst_ + 56) = r##K##_14; *(float4*)(dst_ + 60) = r##K##_15; \
  }
  STOREK(0) STOREK(1) STOREK(2) STOREK(3)
#undef STOREK

  // ---- emit permutation: rowsrc[i] = physical row (abs) holding virtual row i ----
  for (int i = tid; i < R; i += 256) rowsrc[m * 1024 + i] = (unsigned short)(c0 + Vv[i]);
  // ---- logsum: lane-parallel logs + shfl-reduce (wave 0) ----
  if (tid < 64) {
    double lg = log(fabs((double)ujjS[tid]));
    #pragma unroll
    for (int mask = 32; mask; mask >>= 1) lg += __shfl_xor(lg, mask);
    if (tid == 0) atomicAdd(&scores[m], lg);
  }
}

// ======================= permutation-gather + TRSM (width 64) =======================
// Gathers A12 rows via rowsrc, solves U12 = L11^{-1} A12 (unit diag), writes U12
// to consolidated rows c0..c0+63, repairs displaced A22 rows (trailing cols).
__global__ __launch_bounds__(256) void ptrsm_kernel(float* __restrict__ lu,
                                                    const unsigned short* __restrict__ rowsrc,
                                                    int c0, int ncs) {
  const int m  = blockIdx.x / ncs;
  const int cs = blockIdx.x % ncs;
  const int s0 = c0 + 64 + cs * 256;
  const int tid = threadIdx.x;
  const int col = s0 + tid;
  const bool ac = col < N;
  float* A = lu + (size_t)m * NN;
  const int R = N - c0;
  __shared__ int   rowAt[1024];     // content map over rows [c0, N)
  __shared__ float L11s[64][65];
  __shared__ int   dDst[80];
  __shared__ int   dSrc[80];
  __shared__ int   dcount;

  for (int r = tid; r < R; r += 256) rowAt[r] = (int)rowsrc[m * 1024 + r];
  if (tid == 0) dcount = 0;
  __syncthreads();
  // L11 from consolidated panel rows (written by panel_kernel)
  for (int idx = tid; idx < 4096; idx += 256) {
    int i = idx >> 6, k = idx & 63;
    L11s[i][k] = A[(size_t)(c0 + i) * N + c0 + k];
  }
  // collect displaced A22 rows (dst receives content of src); <= 64
  for (int r = 64 + tid; r < R; r += 256) {
    if (rowAt[r] != c0 + r) {
      int i = atomicAdd(&dcount, 1);
      dDst[i] = c0 + r; dSrc[i] = rowAt[r];
    }
  }
  __syncthreads();
  const int nd = dcount;   // <= 64

  // ---- read phase (all loads before any store) ----
  float pay[64];
  #pragma unroll
  for (int i = 0; i < 64; ++i)
    if (i < nd && ac) pay[i] = A[(size_t)dSrc[i] * N + col];
  float u[64];
  #pragma unroll
  for (int i = 0; i < 64; ++i)
    if (ac) u[i] = A[(size_t)rowAt[i] * N + col];

  // ---- TRSM: u = L11^{-1} a12 (unit diag) ----
  #pragma unroll
  for (int i = 1; i < 64; ++i) {
    float a = u[i];
    #pragma unroll
    for (int k = 0; k < 64; ++k)
      if (k < i) a -= L11s[i][k] * u[k];
    u[i] = a;
  }

  // ---- write phase ----
  #pragma unroll
  for (int i = 0; i < 64; ++i)
    if (i < nd && ac) A[(size_t)dDst[i] * N + col] = pay[i];
  #pragma unroll
  for (int i = 0; i < 64; ++i)
    if (ac) A[(size_t)(c0 + i) * N + col] = u[i];
}

// ======================= trailing update: A22 -= L21 @ U12 (K=64) ================
// Fully consolidated inputs: plain indexing, no rowsrc.
__global__ __launch_bounds__(256) void update_kernel(float* __restrict__ lu,
                                                     int c0, int nrt, int ncs) {
  const int per = nrt * ncs;
  const int m  = blockIdx.x / per;
  const int t  = blockIdx.x % per;
  const int rt = t / ncs, cs = t % ncs;
  const int r0 = c0 + 64 + rt * 64;
  const int s0 = c0 + 64 + cs * 128;
  const int tid = threadIdx.x;
  float* A = lu + (size_t)m * NN;
  __shared__ float Lts[64][68];    // L21 tile transposed: [k][r]  (17.4 KB)
  __shared__ float Us[64][132];    // U12 stripe: [k][c]           (33.8 KB)
  for (int idx = tid; idx < 4096; idx += 256) {
    int r = idx >> 6, k = idx & 63;
    Lts[k][r] = (r0 + r < N) ? A[(size_t)(r0 + r) * N + c0 + k] : 0.0f;
  }
  for (int idx = tid; idx < 8192; idx += 256) {
    int k = idx >> 7, c = idx & 127;
    Us[k][c] = (s0 + c < N) ? A[(size_t)(c0 + k) * N + s0 + c] : 0.0f;
  }
  __syncthreads();
  const int tx = tid & 31;    // col group: 4 cols (128 total)
  const int ty = tid >> 5;    // row group: 8 rows (uniform a-reads per wave-half)
  float4 acc[8];
  #pragma unroll
  for (int e = 0; e < 8; ++e) acc[e] = make_float4(0.f, 0.f, 0.f, 0.f);
  #pragma unroll 4
  for (int k = 0; k < 64; ++k) {
    float4 b  = *(const float4*)&Us[k][tx * 4];
    float4 a0 = *(const float4*)&Lts[k][ty * 8 + 0];
    float4 a1 = *(const float4*)&Lts[k][ty * 8 + 4];
    acc[0].x += a0.x*b.x; acc[0].y += a0.x*b.y; acc[0].z += a0.x*b.z; acc[0].w += a0.x*b.w;
    acc[1].x += a0.y*b.x; acc[1].y += a0.y*b.y; acc[1].z += a0.y*b.z; acc[1].w += a0.y*b.w;
    acc[2].x += a0.z*b.x; acc[2].y += a0.z*b.y; acc[2].z += a0.z*b.z; acc[2].w += a0.z*b.w;
    acc[3].x += a0.w*b.x; acc[3].y += a0.w*b.y; acc[3].z += a0.w*b.z; acc[3].w += a0.w*b.w;
    acc[4].x += a1.x*b.x; acc[4].y += a1.x*b.y; acc[4].z += a1.x*b.z; acc[4].w += a1.x*b.w;
    acc[5].x += a1.y*b.x; acc[5].y += a1.y*b.y; acc[5].z += a1.y*b.z; acc[5].w += a1.y*b.w;
    acc[6].x += a1.z*b.x; acc[6].y += a1.z*b.y; acc[6].z += a1.z*b.z; acc[6].w += a1.z*b.w;
    acc[7].x += a1.w*b.x; acc[7].y += a1.w*b.y; acc[7].z += a1.w*b.z; acc[7].w += a1.w*b.w;
  }
  const bool colok = (s0 + tx * 4) < N;
  #pragma unroll
  for (int e = 0; e < 8; ++e) {
    int r = r0 + ty * 8 + e;
    if (r < N && colok) {
      float4* p = (float4*)&A[(size_t)r * N + s0 + tx * 4];
      float4 v = *p;
      v.x -= acc[e].x; v.y -= acc[e].y; v.z -= acc[e].z; v.w -= acc[e].w;
      *p = v;
    }
  }
}

// ======================= gate + top-k + effective weights =======================
__global__ void select_kernel(const void* __restrict__ flagsraw, const double* __restrict__ scores,
                              const float* __restrict__ w1, const float* __restrict__ b1,
                              const float* __restrict__ w2, const float* __restrict__ b2,
                              int* __restrict__ topidx, float* __restrict__ misc,
                              float* __restrict__ out_tail) {
  if (threadIdx.x != 0 || blockIdx.x != 0) return;
  const unsigned char* fb = (const unsigned char*)flagsraw;
  bool nonbin = false, off4 = false;
  for (int i = 0; i < 16; ++i) {
    if (fb[i] > 1) nonbin = true;
    if ((i & 3) && fb[i]) off4 = true;
  }
  int f[16]; int nact = 0;
  for (int i = 0; i < 16; ++i) {
    int v;
    if (nonbin)      v = (((const float*)flagsraw)[i] != 0.0f);
    else if (off4)   v = (fb[i] != 0);
    else             v = (((const int*)flagsraw)[i] != 0);
    f[i] = v; nact += v;
  }
  int gate = (nact >= 4) ? 1 : 0;   // THRESH = 4
  double sc[16];
  for (int i = 0; i < 16; ++i) sc[i] = f[i] ? scores[i] : -1.0e300;
  bool used[16] = {};
  for (int k = 0; k < 8; ++k) {     // descending, ties -> lowest index (lax.top_k)
    int bi = -1; double bv = 0.0;
    for (int i = 0; i < 16; ++i)
      if (!used[i] && (bi < 0 || sc[i] > bv)) { bv = sc[i]; bi = i; }
    used[bi] = true;
    topidx[k] = bi;
  }
  for (int cC = 0; cC < 10; ++cC) {
    float s = 0.0f;
    for (int h = 0; h < 32; ++h) s += w2[h] * w1[h * 10 + cC];
    misc[cC] = s;
  }
  float be = 0.0f;
  for (int h = 0; h < 32; ++h) be += w2[h] * b1[h];
  be += b2[0];
  misc[10] = be;
  ((int*)misc)[12] = gate;
  *out_tail = gate ? 1.0f : 0.0f;
}

// ======================= build combined right-hand matrices M0..M2 =======================
__global__ __launch_bounds__(256) void build_m_kernel(const float* __restrict__ x,
                                                      const int* __restrict__ topidx,
                                                      const float* __restrict__ misc,
                                                      float* __restrict__ M) {
  int i = blockIdx.x * 256 + threadIdx.x;   // 262144 float4 positions
  const float4* T1 = (const float4*)(x + (size_t)topidx[1] * NN);
  const float4* T2 = (const float4*)(x + (size_t)topidx[2] * NN);
  const float4* T3 = (const float4*)(x + (size_t)topidx[3] * NN);
  float w0 = misc[0], w1_ = misc[1], w2_ = misc[2], w3_ = misc[3], w4_ = misc[4], w5_ = misc[5];
  float4 t1 = T1[i], t2 = T2[i], t3 = T3[i];
  float4 m0, m1, m2;
  m0.x = w0 * t1.x + w1_ * t2.x + w2_ * t3.x;
  m0.y = w0 * t1.y + w1_ * t2.y + w2_ * t3.y;
  m0.z = w0 * t1.z + w1_ * t2.z + w2_ * t3.z;
  m0.w = w0 * t1.w + w1_ * t2.w + w2_ * t3.w;
  m1.x = w3_ * t2.x + w4_ * t3.x;
  m1.y = w3_ * t2.y + w4_ * t3.y;
  m1.z = w3_ * t2.z + w4_ * t3.z;
  m1.w = w3_ * t2.w + w4_ * t3.w;
  m2.x = w5_ * t3.x;  m2.y = w5_ * t3.y;  m2.z = w5_ * t3.z;  m2.w = w5_ * t3.w;
  ((float4*)M)[i] = m0;
  ((float4*)(M + NN))[i] = m1;
  ((float4*)(M + 2 * (size_t)NN))[i] = m2;
}

// ======================= split-K final GEMM: P[chunk] = A_chunk @ B_chunk ==========
__global__ __launch_bounds__(256) void final_gemm_kernel(const float* __restrict__ x,
                                                         const float* __restrict__ M,
                                                         const int* __restrict__ topidx,
                                                         float* __restrict__ P) {
  const int chunk = blockIdx.x >> 8;   // 0..5
  const int t  = blockIdx.x & 255;
  const int tr = t >> 4, tc = t & 15;
  const int mi  = chunk >> 1;
  const int k0b = (chunk & 1) << 9;    // 0 or 512
  const float* A = x + (size_t)topidx[mi] * NN;
  const float* B = M + (size_t)mi * NN;
  __shared__ float As[32][68];   // A^T fragment: As[k][r], float4-aligned stride
  __shared__ float Bs[32][68];
  const int ty = threadIdx.x >> 4, tx = threadIdx.x & 15;
  float acc[4][4] = {};
  for (int k0 = k0b; k0 < k0b + 512; k0 += 32) {
    for (int idx = threadIdx.x; idx < 2048; idx += 256) {
      int r = idx >> 5, k = idx & 31;
      As[k][r] = A[(size_t)(tr * 64 + r) * N + k0 + k];
    }
    for (int idx = threadIdx.x; idx < 2048; idx += 256) {
      int k = idx >> 6, cc = idx & 63;
      Bs[k][cc] = B[(size_t)(k0 + k) * N + tc * 64 + cc];
    }
    __syncthreads();
    #pragma unroll 8
    for (int k = 0; k < 32; ++k) {
      float4 a = *(const float4*)&As[k][ty * 4];
      float4 b = *(const float4*)&Bs[k][tx * 4];
      acc[0][0] += a.x * b.x; acc[0][1] += a.x * b.y; acc[0][2] += a.x * b.z; acc[0][3] += a.x * b.w;
      acc[1][0] += a.y * b.x; acc[1][1] += a.y * b.y; acc[1][2] += a.y * b.z; acc[1][3] += a.y * b.w;
      acc[2][0] += a.z * b.x; acc[2][1] += a.z * b.y; acc[2][2] += a.z * b.z; acc[2][3] += a.z * b.w;
      acc[3][0] += a.w * b.x; acc[3][1] += a.w * b.y; acc[3][2] += a.w * b.z; acc[3][3] += a.w * b.w;
    }
    __syncthreads();
  }
  float* Pc = P + (size_t)chunk * NN;
  #pragma unroll
  for (int i = 0; i < 4; ++i) {
    size_t r = (size_t)(tr * 64 + ty * 4 + i);
    float4 v = make_float4(acc[i][0], acc[i][1], acc[i][2], acc[i][3]);
    *(float4*)&Pc[r * N + tc * 64 + tx * 4] = v;
  }
}

// ======================= reduce partials + preserve channels + bias ================
__global__ __launch_bounds__(256) void reduce_out_kernel(const float* __restrict__ x,
                                                         const float* __restrict__ P,
                                                         const int* __restrict__ topidx,
                                                         const float* __restrict__ misc,
                                                         float* __restrict__ out) {
  int i = blockIdx.x * 256 + threadIdx.x;   // 262144 float4 positions
  int gate = ((const int*)misc)[12];
  float4* o = (float4*)out;
  if (!gate) { o[i] = make_float4(0.f, 0.f, 0.f, 0.f); return; }
  float w6 = misc[6], w7 = misc[7], w8 = misc[8], w9 = misc[9], be = misc[10];
  float4 p0 = ((const float4*)(x + (size_t)topidx[4] * NN))[i];
  float4 p1 = ((const float4*)(x + (size_t)topidx[5] * NN))[i];
  float4 p2 = ((const float4*)(x + (size_t)topidx[6] * NN))[i];
  float4 p3 = ((const float4*)(x + (size_t)topidx[7] * NN))[i];
  float4 r;
  r.x = be + w6 * p0.x + w7 * p1.x + w8 * p2.x + w9 * p3.x;
  r.y = be + w6 * p0.y + w7 * p1.y + w8 * p2.y + w9 * p3.y;
  r.z = be + w6 * p0.z + w7 * p1.z + w8 * p2.z + w9 * p3.z;
  r.w = be + w6 * p0.w + w7 * p1.w + w8 * p2.w + w9 * p3.w;
  #pragma unroll
  for (int cN = 0; cN < 6; ++cN) {
    float4 q = ((const float4*)(P + (size_t)cN * NN))[i];
    r.x += q.x; r.y += q.y; r.z += q.z; r.w += q.w;
  }
  o[i] = r;
}

// ======================= host =======================
extern "C" void kernel_launch(void* const* d_in, const int* in_sizes, int n_in,
                              void* d_out, int out_size, void* d_ws, size_t ws_size,
                              hipStream_t stream) {
  const float* x  = (const float*)d_in[0];
  const void*  fl = d_in[1];
  const float* w1 = (const float*)d_in[2];
  const float* b1 = (const float*)d_in[3];
  const float* w2 = (const float*)d_in[4];
  const float* b2 = (const float*)d_in[5];
  float* out = (float*)d_out;

  char* ws = (char*)d_ws;
  float* LU = (float*)ws;                                // 64 MB (dead after LU phase)
  float* Mm = (float*)ws;                                // 12 MB, reuses LU space
  float* P  = (float*)(ws + (size_t)12 * 1024 * 1024);   // 24 MB partials, inside old LU
  size_t tail = (size_t)16 * NN * sizeof(float);         // 67,108,864
  double* scores = (double*)(ws + tail);                 // 16 doubles
  unsigned short* rowsrc = (unsigned short*)(ws + tail + 256);     // 16*1024 u16 = 32 KB
  int*    topidx = (int*)(ws + tail + 256 + 32768);      // 8 ints
  float*  misc   = (float*)(ws + tail + 256 + 32768 + 256); // weff[10], beff, gate

  init_kernel<<<1, 64, 0, stream>>>(scores);
  copy_kernel<<<16384, 256, 0, stream>>>((const float4*)x, (float4*)LU);

  for (int c0 = 0; c0 < N; c0 += 64) {
    panel_kernel<<<16, 256, 0, stream>>>(LU, rowsrc, scores, c0);
    int tcols = N - c0 - 64;
    if (tcols > 0) {
      int ncs = (tcols + 255) / 256;
      ptrsm_kernel<<<16 * ncs, 256, 0, stream>>>(LU, rowsrc, c0, ncs);
      int nrt = (tcols + 63) / 64;
      int ncs2 = (tcols + 127) / 128;
      update_kernel<<<16 * nrt * ncs2, 256, 0, stream>>>(LU, c0, nrt, ncs2);
    }
  }

  select_kernel<<<1, 64, 0, stream>>>(fl, scores, w1, b1, w2, b2, topidx, misc, out + NN);
  build_m_kernel<<<1024, 256, 0, stream>>>(x, topidx, misc, Mm);
  final_gemm_kernel<<<1536, 256, 0, stream>>>(x, Mm, topidx, P);
  reduce_out_kernel<<<1024, 256, 0, stream>>>(x, P, topidx, misc, out);
}

// Round 9
// 5799.770 us; speedup vs baseline: 1.1701x; 1.1701x over previous
//
#include <hip/hip_runtime.h>
#include <math.h>

#define N 1024
#define NN (N*N)

// ======================= init =======================
__global__ void init_kernel(double* scores) {
  int t = threadIdx.x;
  if (t < 16) scores[t] = 0.0;
}

// ======================= copy x -> LU workspace =======================
__global__ __launch_bounds__(256) void copy_kernel(const float4* __restrict__ src,
                                                   float4* __restrict__ dst) {
  int i = blockIdx.x * 256 + threadIdx.x;   // grid sized exactly: 16M floats / 4
  dst[i] = src[i];
}

// ======================= LU panel (width 64): 1024 thr x 1 row ====
// Spill history: >=32 float4/thread at width-64 always demoted to scratch
// (r5:108, r7:84, r8:152 VGPR; 6MB scratch HBM each). This config: ONE row per
// thread = 16 named float4 = 64 data VGPRs, quad-outer U-read (4 transient),
// owner-publish is simply thread pcur (no row-group select chains).
// __launch_bounds__(1024,1) caps at 128 VGPR (4 waves/SIMD) -- ~100 needed.
// Virtual pivoting via Vv/Pv; prow broadcast; fused next-col scan; 2
// barriers/step; consolidating writeback; rowsrc[i] = phys slot of virtual i.
__global__ __launch_bounds__(1024, 1) void panel_kernel(float* __restrict__ lu,
                                                        unsigned short* __restrict__ rowsrc,
                                                        double* __restrict__ scores,
                                                        int c0) {
  __shared__ __align__(16) float prow[64];   // pivot row broadcast buffer
  __shared__ float ujjS[64];
  __shared__ float redv[2][16];              // parity-buffered cross-wave reduce
  __shared__ int   redk[2][16];
  __shared__ int Vv[1024];                   // virtual -> physical (rel c0)
  __shared__ int Pv[1024];                   // physical -> virtual
  const int m = blockIdx.x;
  float* A = lu + (size_t)m * NN;
  const int R = N - c0;
  const int tid = threadIdx.x;
  const int wid = tid >> 6;                  // wave id 0..15

  const float4 z4 = make_float4(0.f, 0.f, 0.f, 0.f);
  float4 q_0=z4, q_1=z4, q_2=z4, q_3=z4, q_4=z4, q_5=z4, q_6=z4, q_7=z4;
  float4 q_8=z4, q_9=z4, q_10=z4, q_11=z4, q_12=z4, q_13=z4, q_14=z4, q_15=z4;

  const bool ld_ = (tid < R);
  bool act_ = ld_;

  if (ld_) {
    const float* src_ = A + (size_t)(c0 + tid) * N + c0;
    q_0  = *(const float4*)(src_ +  0);  q_1  = *(const float4*)(src_ +  4);
    q_2  = *(const float4*)(src_ +  8);  q_3  = *(const float4*)(src_ + 12);
    q_4  = *(const float4*)(src_ + 16);  q_5  = *(const float4*)(src_ + 20);
    q_6  = *(const float4*)(src_ + 24);  q_7  = *(const float4*)(src_ + 28);
    q_8  = *(const float4*)(src_ + 32);  q_9  = *(const float4*)(src_ + 36);
    q_10 = *(const float4*)(src_ + 40);  q_11 = *(const float4*)(src_ + 44);
    q_12 = *(const float4*)(src_ + 48);  q_13 = *(const float4*)(src_ + 52);
    q_14 = *(const float4*)(src_ + 56);  q_15 = *(const float4*)(src_ + 60);
  }

  if (tid < R) { Vv[tid] = tid; Pv[tid] = tid; }

  // ---- prescan: pivot for column 0 ----
  {
    float bval = -1.0f; int brow = 0x7fffffff;
    if (act_) { bval = fabsf(q_0.x); brow = tid; }
    #pragma unroll
    for (int mask = 32; mask; mask >>= 1) {
      float ov = __shfl_xor(bval, mask);
      int   orr = __shfl_xor(brow, mask);
      if (ov > bval || (ov == bval && orr < brow)) { bval = ov; brow = orr; }
    }
    if ((tid & 63) == 0) { redv[0][wid] = bval; redk[0][wid] = brow; }
  }
  __syncthreads();   // redv[0] + Vv/Pv init visible

  #pragma unroll 1
  for (int j = 0; j < 64; ++j) {
    // ---- combine 16-wave partials -> physical pivot row pcur (redundant, all) ----
    int pcur;
    {
      const int pb = j & 1;
      float bv = redv[pb][0]; int bk = redk[pb][0];
      #pragma unroll
      for (int w = 1; w < 16; ++w) {
        float vw = redv[pb][w]; int kw = redk[pb][w];
        if (vw > bv || (vw == bv && kw < bk)) { bv = vw; bk = kw; }
      }
      pcur = bk;
    }
    // ---- owner (thread pcur) publishes pivot row from registers; retires it ----
    if (tid == pcur) {
      float4* pd = (float4*)prow;
      pd[0]  = q_0;  pd[1]  = q_1;  pd[2]  = q_2;  pd[3]  = q_3;
      pd[4]  = q_4;  pd[5]  = q_5;  pd[6]  = q_6;  pd[7]  = q_7;
      pd[8]  = q_8;  pd[9]  = q_9;  pd[10] = q_10; pd[11] = q_11;
      pd[12] = q_12; pd[13] = q_13; pd[14] = q_14; pd[15] = q_15;
      act_ = false;
    }
    // ---- thread 0: maintain virtual<->physical permutation ----
    if (tid == 0) {
      int b  = Pv[pcur];                // virtual index of pivot (>= j)
      int pa = Vv[j];
      Vv[j] = pcur; Vv[b] = pa;
      Pv[pcur] = j; Pv[pa] = b;
    }
    __syncthreads();   // B1: prow visible

    const float ujj = prow[j];
    if (tid == 0) ujjS[j] = ujj;
    const float rujj = 1.0f / ujj;
    const int qj = j >> 2, ej = j & 3;
    const int jn = j + 1;
    const int qn = (j < 63) ? (jn >> 2) : -1, en = jn & 3;

    // ---- quad-outer update of the single owned row; fused next-col scan ----
    float l = 0.0f, nv = 0.0f;
#define QS(Q) { \
      if (Q >= qj) { \
        const float4 uq = *(const float4*)&prow[4 * Q]; \
        if (act_) { \
          float4 v = q_##Q; \
          if (Q == qj) { \
            float aj = (ej == 0) ? v.x : (ej == 1) ? v.y : (ej == 2) ? v.z : v.w; \
            l = aj * rujj; \
            if (ej == 0)      { v.x = l; v.y -= l * uq.y; v.z -= l * uq.z; v.w -= l * uq.w; } \
            else if (ej == 1) { v.y = l; v.z -= l * uq.z; v.w -= l * uq.w; } \
            else if (ej == 2) { v.z = l; v.w -= l * uq.w; } \
            else              { v.w = l; } \
          } else { \
            v.x -= l * uq.x; v.y -= l * uq.y; v.z -= l * uq.z; v.w -= l * uq.w; \
          } \
          if (Q == qn) nv = (en == 0) ? v.x : (en == 1) ? v.y : (en == 2) ? v.z : v.w; \
          q_##Q = v; \
        } \
      } \
    }
    QS(0) QS(1) QS(2) QS(3) QS(4) QS(5) QS(6) QS(7)
    QS(8) QS(9) QS(10) QS(11) QS(12) QS(13) QS(14) QS(15)
#undef QS

    if (j < 63) {
      float bval = -1.0f; int brow = 0x7fffffff;
      if (act_) { bval = fabsf(nv); brow = tid; }
      #pragma unroll
      for (int mask = 32; mask; mask >>= 1) {
        float ov = __shfl_xor(bval, mask);
        int   orr = __shfl_xor(brow, mask);
        if (ov > bval || (ov == bval && orr < brow)) { bval = ov; brow = orr; }
      }
      if ((tid & 63) == 0) { redv[jn & 1][wid] = bval; redk[jn & 1][wid] = brow; }
    }
    __syncthreads();   // B2: updates done reading prow; redv visible for next step
  }

  // ---- CONSOLIDATED writeback: phys slot tid's content -> physical row c0+Pv[tid] ----
  if (ld_) {
    float* dst_ = A + (size_t)(c0 + Pv[tid]) * N + c0;
    *(float4*)(dst_ +  0) = q_0;   *(float4*)(dst_ +  4) = q_1;
    *(float4*)(dst_ +  8) = q_2;   *(float4*)(dst_ + 12) = q_3;
    *(float4*)(dst_ + 16) = q_4;   *(float4*)(dst_ + 20) = q_5;
    *(float4*)(dst_ + 24) = q_6;   *(float4*)(dst_ + 28) = q_7;
    *(float4*)(dst_ + 32) = q_8;   *(float4*)(dst_ + 36) = q_9;
    *(float4*)(dst_ + 40) = q_10;  *(float4*)(dst_ + 44) = q_11;
    *(float4*)(dst_ + 48) = q_12;  *(float4*)(dst_ + 52) = q_13;
    *(float4*)(dst_ + 56) = q_14;  *(float4*)(dst_ + 60) = q_15;
  }

  // ---- emit permutation: rowsrc[i] = physical row (abs) holding virtual row i ----
  if (tid < R) rowsrc[m * 1024 + tid] = (unsigned short)(c0 + Vv[tid]);
  // ---- logsum: lane-parallel logs + shfl-reduce (wave 0) ----
  if (tid < 64) {
    double lg = log(fabs((double)ujjS[tid]));
    #pragma unroll
    for (int mask = 32; mask; mask >>= 1) lg += __shfl_xor(lg, mask);
    if (tid == 0) atomicAdd(&scores[m], lg);
  }
}

// ======================= permutation-gather + TRSM (width 64) =======================
// Gathers A12 rows via rowsrc, solves U12 = L11^{-1} A12 (unit diag), writes U12
// to consolidated rows c0..c0+63, repairs displaced A22 rows (trailing cols).
__global__ __launch_bounds__(256) void ptrsm_kernel(float* __restrict__ lu,
                                                    const unsigned short* __restrict__ rowsrc,
                                                    int c0, int ncs) {
  const int m  = blockIdx.x / ncs;
  const int cs = blockIdx.x % ncs;
  const int s0 = c0 + 64 + cs * 256;
  const int tid = threadIdx.x;
  const int col = s0 + tid;
  const bool ac = col < N;
  float* A = lu + (size_t)m * NN;
  const int R = N - c0;
  __shared__ int   rowAt[1024];     // content map over rows [c0, N)
  __shared__ float L11s[64][65];
  __shared__ int   dDst[80];
  __shared__ int   dSrc[80];
  __shared__ int   dcount;

  for (int r = tid; r < R; r += 256) rowAt[r] = (int)rowsrc[m * 1024 + r];
  if (tid == 0) dcount = 0;
  __syncthreads();
  // L11 from consolidated panel rows (written by panel_kernel)
  for (int idx = tid; idx < 4096; idx += 256) {
    int i = idx >> 6, k = idx & 63;
    L11s[i][k] = A[(size_t)(c0 + i) * N + c0 + k];
  }
  // collect displaced A22 rows (dst receives content of src); <= 64
  for (int r = 64 + tid; r < R; r += 256) {
    if (rowAt[r] != c0 + r) {
      int i = atomicAdd(&dcount, 1);
      dDst[i] = c0 + r; dSrc[i] = rowAt[r];
    }
  }
  __syncthreads();
  const int nd = dcount;   // <= 64

  // ---- read phase (all loads before any store) ----
  float pay[64];
  #pragma unroll
  for (int i = 0; i < 64; ++i)
    if (i < nd && ac) pay[i] = A[(size_t)dSrc[i] * N + col];
  float u[64];
  #pragma unroll
  for (int i = 0; i < 64; ++i)
    if (ac) u[i] = A[(size_t)rowAt[i] * N + col];

  // ---- TRSM: u = L11^{-1} a12 (unit diag) ----
  #pragma unroll
  for (int i = 1; i < 64; ++i) {
    float a = u[i];
    #pragma unroll
    for (int k = 0; k < 64; ++k)
      if (k < i) a -= L11s[i][k] * u[k];
    u[i] = a;
  }

  // ---- write phase ----
  #pragma unroll
  for (int i = 0; i < 64; ++i)
    if (i < nd && ac) A[(size_t)dDst[i] * N + col] = pay[i];
  #pragma unroll
  for (int i = 0; i < 64; ++i)
    if (ac) A[(size_t)(c0 + i) * N + col] = u[i];
}

// ======================= trailing update: A22 -= L21 @ U12 (K=64) ================
// Fully consolidated inputs: plain indexing, no rowsrc.
__global__ __launch_bounds__(256) void update_kernel(float* __restrict__ lu,
                                                     int c0, int nrt, int ncs) {
  const int per = nrt * ncs;
  const int m  = blockIdx.x / per;
  const int t  = blockIdx.x % per;
  const int rt = t / ncs, cs = t % ncs;
  const int r0 = c0 + 64 + rt * 64;
  const int s0 = c0 + 64 + cs * 128;
  const int tid = threadIdx.x;
  float* A = lu + (size_t)m * NN;
  __shared__ float Lts[64][68];    // L21 tile transposed: [k][r]  (17.4 KB)
  __shared__ float Us[64][132];    // U12 stripe: [k][c]           (33.8 KB)
  for (int idx = tid; idx < 4096; idx += 256) {
    int r = idx >> 6, k = idx & 63;
    Lts[k][r] = (r0 + r < N) ? A[(size_t)(r0 + r) * N + c0 + k] : 0.0f;
  }
  for (int idx = tid; idx < 8192; idx += 256) {
    int k = idx >> 7, c = idx & 127;
    Us[k][c] = (s0 + c < N) ? A[(size_t)(c0 + k) * N + s0 + c] : 0.0f;
  }
  __syncthreads();
  const int tx = tid & 31;    // col group: 4 cols (128 total)
  const int ty = tid >> 5;    // row group: 8 rows (uniform a-reads per wave-half)
  float4 acc[8];
  #pragma unroll
  for (int e = 0; e < 8; ++e) acc[e] = make_float4(0.f, 0.f, 0.f, 0.f);
  #pragma unroll 4
  for (int k = 0; k < 64; ++k) {
    float4 b  = *(const float4*)&Us[k][tx * 4];
    float4 a0 = *(const float4*)&Lts[k][ty * 8 + 0];
    float4 a1 = *(const float4*)&Lts[k][ty * 8 + 4];
    acc[0].x += a0.x*b.x; acc[0].y += a0.x*b.y; acc[0].z += a0.x*b.z; acc[0].w += a0.x*b.w;
    acc[1].x += a0.y*b.x; acc[1].y += a0.y*b.y; acc[1].z += a0.y*b.z; acc[1].w += a0.y*b.w;
    acc[2].x += a0.z*b.x; acc[2].y += a0.z*b.y; acc[2].z += a0.z*b.z; acc[2].w += a0.z*b.w;
    acc[3].x += a0.w*b.x; acc[3].y += a0.w*b.y; acc[3].z += a0.w*b.z; acc[3].w += a0.w*b.w;
    acc[4].x += a1.x*b.x; acc[4].y += a1.x*b.y; acc[4].z += a1.x*b.z; acc[4].w += a1.x*b.w;
    acc[5].x += a1.y*b.x; acc[5].y += a1.y*b.y; acc[5].z += a1.y*b.z; acc[5].w += a1.y*b.w;
    acc[6].x += a1.z*b.x; acc[6].y += a1.z*b.y; acc[6].z += a1.z*b.z; acc[6].w += a1.z*b.w;
    acc[7].x += a1.w*b.x; acc[7].y += a1.w*b.y; acc[7].z += a1.w*b.z; acc[7].w += a1.w*b.w;
  }
  const bool colok = (s0 + tx * 4) < N;
  #pragma unroll
  for (int e = 0; e < 8; ++e) {
    int r = r0 + ty * 8 + e;
    if (r < N && colok) {
      float4* p = (float4*)&A[(size_t)r * N + s0 + tx * 4];
      float4 v = *p;
      v.x -= acc[e].x; v.y -= acc[e].y; v.z -= acc[e].z; v.w -= acc[e].w;
      *p = v;
    }
  }
}

// ======================= gate + top-k + effective weights =======================
__global__ void select_kernel(const void* __restrict__ flagsraw, const double* __restrict__ scores,
                              const float* __restrict__ w1, const float* __restrict__ b1,
                              const float* __restrict__ w2, const float* __restrict__ b2,
                              int* __restrict__ topidx, float* __restrict__ misc,
                              float* __restrict__ out_tail) {
  if (threadIdx.x != 0 || blockIdx.x != 0) return;
  const unsigned char* fb = (const unsigned char*)flagsraw;
  bool nonbin = false, off4 = false;
  for (int i = 0; i < 16; ++i) {
    if (fb[i] > 1) nonbin = true;
    if ((i & 3) && fb[i]) off4 = true;
  }
  int f[16]; int nact = 0;
  for (int i = 0; i < 16; ++i) {
    int v;
    if (nonbin)      v = (((const float*)flagsraw)[i] != 0.0f);
    else if (off4)   v = (fb[i] != 0);
    else             v = (((const int*)flagsraw)[i] != 0);
    f[i] = v; nact += v;
  }
  int gate = (nact >= 4) ? 1 : 0;   // THRESH = 4
  double sc[16];
  for (int i = 0; i < 16; ++i) sc[i] = f[i] ? scores[i] : -1.0e300;
  bool used[16] = {};
  for (int k = 0; k < 8; ++k) {     // descending, ties -> lowest index (lax.top_k)
    int bi = -1; double bv = 0.0;
    for (int i = 0; i < 16; ++i)
      if (!used[i] && (bi < 0 || sc[i] > bv)) { bv = sc[i]; bi = i; }
    used[bi] = true;
    topidx[k] = bi;
  }
  for (int cC = 0; cC < 10; ++cC) {
    float s = 0.0f;
    for (int h = 0; h < 32; ++h) s += w2[h] * w1[h * 10 + cC];
    misc[cC] = s;
  }
  float be = 0.0f;
  for (int h = 0; h < 32; ++h) be += w2[h] * b1[h];
  be += b2[0];
  misc[10] = be;
  ((int*)misc)[12] = gate;
  *out_tail = gate ? 1.0f : 0.0f;
}

// ======================= build combined right-hand matrices M0..M2 =======================
__global__ __launch_bounds__(256) void build_m_kernel(const float* __restrict__ x,
                                                      const int* __restrict__ topidx,
                                                      const float* __restrict__ misc,
                                                      float* __restrict__ M) {
  int i = blockIdx.x * 256 + threadIdx.x;   // 262144 float4 positions
  const float4* T1 = (const float4*)(x + (size_t)topidx[1] * NN);
  const float4* T2 = (const float4*)(x + (size_t)topidx[2] * NN);
  const float4* T3 = (const float4*)(x + (size_t)topidx[3] * NN);
  float w0 = misc[0], w1_ = misc[1], w2_ = misc[2], w3_ = misc[3], w4_ = misc[4], w5_ = misc[5];
  float4 t1 = T1[i], t2 = T2[i], t3 = T3[i];
  float4 m0, m1, m2;
  m0.x = w0 * t1.x + w1_ * t2.x + w2_ * t3.x;
  m0.y = w0 * t1.y + w1_ * t2.y + w2_ * t3.y;
  m0.z = w0 * t1.z + w1_ * t2.z + w2_ * t3.z;
  m0.w = w0 * t1.w + w1_ * t2.w + w2_ * t3.w;
  m1.x = w3_ * t2.x + w4_ * t3.x;
  m1.y = w3_ * t2.y + w4_ * t3.y;
  m1.z = w3_ * t2.z + w4_ * t3.z;
  m1.w = w3_ * t2.w + w4_ * t3.w;
  m2.x = w5_ * t3.x;  m2.y = w5_ * t3.y;  m2.z = w5_ * t3.z;  m2.w = w5_ * t3.w;
  ((float4*)M)[i] = m0;
  ((float4*)(M + NN))[i] = m1;
  ((float4*)(M + 2 * (size_t)NN))[i] = m2;
}

// ======================= split-K final GEMM: P[chunk] = A_chunk @ B_chunk ==========
__global__ __launch_bounds__(256) void final_gemm_kernel(const float* __restrict__ x,
                                                         const float* __restrict__ M,
                                                         const int* __restrict__ topidx,
                                                         float* __restrict__ P) {
  const int chunk = blockIdx.x >> 8;   // 0..5
  const int t  = blockIdx.x & 255;
  const int tr = t >> 4, tc = t & 15;
  const int mi  = chunk >> 1;
  const int k0b = (chunk & 1) << 9;    // 0 or 512
  const float* A = x + (size_t)topidx[mi] * NN;
  const float* B = M + (size_t)mi * NN;
  __shared__ float As[32][68];   // A^T fragment: As[k][r], float4-aligned stride
  __shared__ float Bs[32][68];
  const int ty = threadIdx.x >> 4, tx = threadIdx.x & 15;
  float acc[4][4] = {};
  for (int k0 = k0b; k0 < k0b + 512; k0 += 32) {
    for (int idx = threadIdx.x; idx < 2048; idx += 256) {
      int r = idx >> 5, k = idx & 31;
      As[k][r] = A[(size_t)(tr * 64 + r) * N + k0 + k];
    }
    for (int idx = threadIdx.x; idx < 2048; idx += 256) {
      int k = idx >> 6, cc = idx & 63;
      Bs[k][cc] = B[(size_t)(k0 + k) * N + tc * 64 + cc];
    }
    __syncthreads();
    #pragma unroll 8
    for (int k = 0; k < 32; ++k) {
      float4 a = *(const float4*)&As[k][ty * 4];
      float4 b = *(const float4*)&Bs[k][tx * 4];
      acc[0][0] += a.x * b.x; acc[0][1] += a.x * b.y; acc[0][2] += a.x * b.z; acc[0][3] += a.x * b.w;
      acc[1][0] += a.y * b.x; acc[1][1] += a.y * b.y; acc[1][2] += a.y * b.z; acc[1][3] += a.y * b.w;
      acc[2][0] += a.z * b.x; acc[2][1] += a.z * b.y; acc[2][2] += a.z * b.z; acc[2][3] += a.z * b.w;
      acc[3][0] += a.w * b.x; acc[3][1] += a.w * b.y; acc[3][2] += a.w * b.z; acc[3][3] += a.w * b.w;
    }
    __syncthreads();
  }
  float* Pc = P + (size_t)chunk * NN;
  #pragma unroll
  for (int i = 0; i < 4; ++i) {
    size_t r = (size_t)(tr * 64 + ty * 4 + i);
    float4 v = make_float4(acc[i][0], acc[i][1], acc[i][2], acc[i][3]);
    *(float4*)&Pc[r * N + tc * 64 + tx * 4] = v;
  }
}

// ======================= reduce partials + preserve channels + bias ================
__global__ __launch_bounds__(256) void reduce_out_kernel(const float* __restrict__ x,
                                                         const float* __restrict__ P,
                                                         const int* __restrict__ topidx,
                                                         const float* __restrict__ misc,
                                                         float* __restrict__ out) {
  int i = blockIdx.x * 256 + threadIdx.x;   // 262144 float4 positions
  int gate = ((const int*)misc)[12];
  float4* o = (float4*)out;
  if (!gate) { o[i] = make_float4(0.f, 0.f, 0.f, 0.f); return; }
  float w6 = misc[6], w7 = misc[7], w8 = misc[8], w9 = misc[9], be = misc[10];
  float4 p0 = ((const float4*)(x + (size_t)topidx[4] * NN))[i];
  float4 p1 = ((const float4*)(x + (size_t)topidx[5] * NN))[i];
  float4 p2 = ((const float4*)(x + (size_t)topidx[6] * NN))[i];
  float4 p3 = ((const float4*)(x + (size_t)topidx[7] * NN))[i];
  float4 r;
  r.x = be + w6 * p0.x + w7 * p1.x + w8 * p2.x + w9 * p3.x;
  r.y = be + w6 * p0.y + w7 * p1.y + w8 * p2.y + w9 * p3.y;
  r.z = be + w6 * p0.z + w7 * p1.z + w8 * p2.z + w9 * p3.z;
  r.w = be + w6 * p0.w + w7 * p1.w + w8 * p2.w + w9 * p3.w;
  #pragma unroll
  for (int cN = 0; cN < 6; ++cN) {
    float4 q = ((const float4*)(P + (size_t)cN * NN))[i];
    r.x += q.x; r.y += q.y; r.z += q.z; r.w += q.w;
  }
  o[i] = r;
}

// ======================= host =======================
extern "C" void kernel_launch(void* const* d_in, const int* in_sizes, int n_in,
                              void* d_out, int out_size, void* d_ws, size_t ws_size,
                              hipStream_t stream) {
  const float* x  = (const float*)d_in[0];
  const void*  fl = d_in[1];
  const float* w1 = (const float*)d_in[2];
  const float* b1 = (const float*)d_in[3];
  const float* w2 = (const float*)d_in[4];
  const float* b2 = (const float*)d_in[5];
  float* out = (float*)d_out;

  char* ws = (char*)d_ws;
  float* LU = (float*)ws;                                // 64 MB (dead after LU phase)
  float* Mm = (float*)ws;                                // 12 MB, reuses LU space
  float* P  = (float*)(ws + (size_t)12 * 1024 * 1024);   // 24 MB partials, inside old LU
  size_t tail = (size_t)16 * NN * sizeof(float);         // 67,108,864
  double* scores = (double*)(ws + tail);                 // 16 doubles
  unsigned short* rowsrc = (unsigned short*)(ws + tail + 256);     // 16*1024 u16 = 32 KB
  int*    topidx = (int*)(ws + tail + 256 + 32768);      // 8 ints
  float*  misc   = (float*)(ws + tail + 256 + 32768 + 256); // weff[10], beff, gate

  init_kernel<<<1, 64, 0, stream>>>(scores);
  copy_kernel<<<16384, 256, 0, stream>>>((const float4*)x, (float4*)LU);

  for (int c0 = 0; c0 < N; c0 += 64) {
    panel_kernel<<<16, 1024, 0, stream>>>(LU, rowsrc, scores, c0);
    int tcols = N - c0 - 64;
    if (tcols > 0) {
      int ncs = (tcols + 255) / 256;
      ptrsm_kernel<<<16 * ncs, 256, 0, stream>>>(LU, rowsrc, c0, ncs);
      int nrt = (tcols + 63) / 64;
      int ncs2 = (tcols + 127) / 128;
      update_kernel<<<16 * nrt * ncs2, 256, 0, stream>>>(LU, c0, nrt, ncs2);
    }
  }

  select_kernel<<<1, 64, 0, stream>>>(fl, scores, w1, b1, w2, b2, topidx, misc, out + NN);
  build_m_kernel<<<1024, 256, 0, stream>>>(x, topidx, misc, Mm);
  final_gemm_kernel<<<1536, 256, 0, stream>>>(x, Mm, topidx, P);
  reduce_out_kernel<<<1024, 256, 0, stream>>>(x, P, topidx, misc, out);
}

// Round 10
// 5559.394 us; speedup vs baseline: 1.2207x; 1.0432x over previous
//
#include <hip/hip_runtime.h>
#include <math.h>

#define N 1024
#define NN (N*N)

// ======================= init =======================
__global__ void init_kernel(double* scores) {
  int t = threadIdx.x;
  if (t < 16) scores[t] = 0.0;
}

// ======================= copy x -> LU workspace =======================
__global__ __launch_bounds__(256) void copy_kernel(const float4* __restrict__ src,
                                                   float4* __restrict__ dst) {
  int i = blockIdx.x * 256 + threadIdx.x;   // grid sized exactly: 16M floats / 4
  dst[i] = src[i];
}

// ======================= 32-col LDS factor loop (R0-proven shape) ==============
// Factors cols [0,32) of the LDS tile among slots [rowoff, R): partial pivoting
// (argmax |col|, tie -> min slot), physical LDS row swaps + origin[] swaps,
// fused next-column scan, 2 barriers/step. 256 threads, 4 slots/thread.
__device__ __forceinline__ void factor32(float* __restrict__ sh, int* __restrict__ origin,
                                         float* __restrict__ ujjS,
                                         float (*redv)[4], int (*redk)[4],
                                         int rowoff, int R, int tid) {
  // prescan: pivot for column 0
  {
    float bval = -1.0f; int brow = 0x7fffffff;
    #pragma unroll
    for (int t4 = 0; t4 < 4; ++t4) {
      int r = tid + (t4 << 8);
      if (r >= rowoff && r < R) {
        float v = fabsf(sh[r * 36]);
        if (v > bval || (v == bval && r < brow)) { bval = v; brow = r; }
      }
    }
    #pragma unroll
    for (int mask = 32; mask; mask >>= 1) {
      float ov = __shfl_xor(bval, mask);
      int   orr = __shfl_xor(brow, mask);
      if (ov > bval || (ov == bval && orr < brow)) { bval = ov; brow = orr; }
    }
    if ((tid & 63) == 0) { redv[0][tid >> 6] = bval; redk[0][tid >> 6] = brow; }
  }
  __syncthreads();

  #pragma unroll 1
  for (int jc = 0; jc < 32; ++jc) {
    const int j = rowoff + jc;          // diagonal slot
    int pcur;
    {
      const int pb = jc & 1;
      float bv = redv[pb][0]; int bk = redk[pb][0];
      float v1 = redv[pb][1]; int k1 = redk[pb][1];
      float v2 = redv[pb][2]; int k2 = redk[pb][2];
      float v3 = redv[pb][3]; int k3 = redk[pb][3];
      if (v1 > bv || (v1 == bv && k1 < bk)) { bv = v1; bk = k1; }
      if (v2 > bv || (v2 == bv && k2 < bk)) { bv = v2; bk = k2; }
      if (v3 > bv || (v3 == bv && k3 < bk)) { bv = v3; bk = k3; }
      pcur = bk;
    }
    // swap slots j <-> pcur (full 32-col rows; lanes 0..7) + origin map
    if (pcur != j && tid < 8) {
      float4 a = *(float4*)&sh[j * 36 + 4 * tid];
      float4 b = *(float4*)&sh[pcur * 36 + 4 * tid];
      *(float4*)&sh[j * 36 + 4 * tid] = b;
      *(float4*)&sh[pcur * 36 + 4 * tid] = a;
    }
    if (tid == 0 && pcur != j) {
      int t = origin[j]; origin[j] = origin[pcur]; origin[pcur] = t;
    }
    __syncthreads();   // B1: swap visible

    const int qj = jc >> 2, ej = jc & 3;
    const int jn = jc + 1;
    const int qn = (jc < 31) ? (jn >> 2) : -1, en = jn & 3;
    const float ujj = sh[j * 36 + jc];
    if (tid == 0) ujjS[jc] = ujj;
    const float rujj = 1.0f / ujj;

    float4 u4[8];
    #pragma unroll
    for (int q = 0; q < 8; ++q)
      if (4 * q + 3 >= jc) u4[q] = *(const float4*)&sh[j * 36 + 4 * q];

    float bval = -1.0f; int brow = 0x7fffffff;
    #pragma unroll
    for (int t4 = 0; t4 < 4; ++t4) {
      int r = tid + (t4 << 8);
      if (r > j && r < R) {
        float* rp = &sh[r * 36];
        float l = 0.0f, nv = 0.0f;
        #pragma unroll
        for (int q = 0; q < 8; ++q) {
          if (q < qj) continue;                  // uniform runtime guard
          float4 v = *(float4*)&rp[4 * q];
          if (q == qj) {
            float aj = (ej == 0) ? v.x : (ej == 1) ? v.y : (ej == 2) ? v.z : v.w;
            l = aj * rujj;
            if (ej == 0)      { v.x = l; v.y -= l * u4[q].y; v.z -= l * u4[q].z; v.w -= l * u4[q].w; }
            else if (ej == 1) { v.y = l; v.z -= l * u4[q].z; v.w -= l * u4[q].w; }
            else if (ej == 2) { v.z = l; v.w -= l * u4[q].w; }
            else              { v.w = l; }
          } else {
            v.x -= l * u4[q].x; v.y -= l * u4[q].y;
            v.z -= l * u4[q].z; v.w -= l * u4[q].w;
          }
          if (q == qn)
            nv = (en == 0) ? v.x : (en == 1) ? v.y : (en == 2) ? v.z : v.w;
          *(float4*)&rp[4 * q] = v;
        }
        if (jc < 31) {
          float av = fabsf(nv);
          if (av > bval || (av == bval && r < brow)) { bval = av; brow = r; }
        }
      }
    }
    if (jc < 31) {
      #pragma unroll
      for (int mask = 32; mask; mask >>= 1) {
        float ov = __shfl_xor(bval, mask);
        int   orr = __shfl_xor(brow, mask);
        if (ov > bval || (ov == bval && orr < brow)) { bval = ov; brow = orr; }
      }
      if ((tid & 63) == 0) { redv[jn & 1][tid >> 6] = bval; redk[jn & 1][tid >> 6] = brow; }
    }
    __syncthreads();   // B2
  }
}

// ======================= LU panel (width 64): two-stage LDS panel ===============
// One launch factors a 64-wide panel entirely at LDS speed:
//   A: factor cols [c0,c0+32) in LDS (all R slots), origin[] tracks source rows.
//   stash L11a; write L-cols to global at origin[s] (unconsolidated).
//   B: load cols [c0+32,c0+64) of top 32 virtual rows; TRSM -> U12 in LDS;
//      per slot>=32: brow = global B-row - Lrow(LDS) @ U12, into LDS.
//   C: factor cols [c0+32,c0+64) among slots >= 32 (same loop, rowoff=32).
//   Consolidate: B-cols from LDS -> row c0+s; A-cols global->LDS->global permute.
// Emits rowsrc[i] = physical row holding virtual row i (trailing cols), i.e.
// the R7 ptrsm64/update64 contract (those kernels unchanged, verified 3 runs).
__global__ __launch_bounds__(256, 1) void panel_kernel(float* __restrict__ lu,
                                                       unsigned short* __restrict__ rowsrc,
                                                       double* __restrict__ scores,
                                                       int c0) {
  __shared__ __align__(16) float sh[1024 * 36];   // 147,456 B
  __shared__ float L11s[32][33];                  // 4,224 B
  __shared__ int   origin[1024];                  // 4,096 B
  __shared__ float ujjS[64];
  __shared__ float redv[2][4];
  __shared__ int   redk[2][4];
  const int m = blockIdx.x;
  float* A = lu + (size_t)m * NN;
  const int R = N - c0;
  const int tid = threadIdx.x;

  // ---- load A-panel cols [c0, c0+32) (consolidated by previous step) ----
  #pragma unroll 1
  for (int t4 = 0; t4 < 4; ++t4) {
    int s = tid + (t4 << 8);
    if (s < R) {
      const float* src_ = A + (size_t)(c0 + s) * N + c0;
      float* d = &sh[s * 36];
      #pragma unroll
      for (int q = 0; q < 8; ++q) *(float4*)(d + 4 * q) = *(const float4*)(src_ + 4 * q);
    }
  }
  for (int i = tid; i < R; i += 256) origin[i] = c0 + i;
  // (visibility of loads/origin covered by factor32's prescan barrier)

  // ---- phase A: factor cols 0..31 ----
  factor32(sh, origin, ujjS, redv, redk, 0, R, tid);

  // ---- stash L11a + write A-cols (L/U11 part) to global at origin[s] ----
  for (int idx = tid; idx < 1024; idx += 256) {
    int i = idx >> 5, k = idx & 31;
    L11s[i][k] = sh[i * 36 + k];
  }
  #pragma unroll 1
  for (int t4 = 0; t4 < 4; ++t4) {
    int s = tid + (t4 << 8);
    if (s < R) {
      float* g = A + (size_t)origin[s] * N + c0;
      const float* sp = &sh[s * 36];
      #pragma unroll
      for (int q = 0; q < 8; ++q) *(float4*)(g + 4 * q) = *(const float4*)(sp + 4 * q);
    }
  }
  __syncthreads();   // L11s + A-col writes ordered before sh[0..31] overwrite

  // ---- B: load top-32 B-cols, TRSM U12 = L11a^{-1} A12 ----
  if (tid < 32) {
    const float* g = A + (size_t)origin[tid] * N + c0 + 32;
    float* d = &sh[tid * 36];
    #pragma unroll
    for (int q = 0; q < 8; ++q) *(float4*)(d + 4 * q) = *(const float4*)(g + 4 * q);
  }
  __syncthreads();
  {
    const int c = tid & 31;
    const int rg = tid >> 5;           // 8 groups x 4 rows
    #pragma unroll 1
    for (int k = 0; k < 31; ++k) {
      #pragma unroll
      for (int i = 0; i < 4; ++i) {
        int r = rg * 4 + i;
        if (r > k) sh[r * 36 + c] -= L11s[r][k] * sh[k * 36 + c];
      }
      __syncthreads();
    }
  }
  __syncthreads();

  // ---- stream-update slots >= 32: brow = B_global - Lrow(LDS) @ U12(LDS) ----
  #pragma unroll 1
  for (int t4 = 0; t4 < 4; ++t4) {
    int s = tid + (t4 << 8);
    if (s >= 32 && s < R) {
      const float* g = A + (size_t)origin[s] * N + c0 + 32;
      float4 bq[8];
      #pragma unroll
      for (int q = 0; q < 8; ++q) bq[q] = *(const float4*)(g + 4 * q);
      const float* Lr = &sh[s * 36];
      #pragma unroll 1
      for (int kk = 0; kk < 32; ++kk) {
        float lk = Lr[kk];
        const float4* u = (const float4*)&sh[kk * 36];
        #pragma unroll
        for (int q = 0; q < 8; ++q) {
          float4 uq = u[q];
          bq[q].x -= lk * uq.x; bq[q].y -= lk * uq.y;
          bq[q].z -= lk * uq.z; bq[q].w -= lk * uq.w;
        }
      }
      float* d = &sh[s * 36];
      #pragma unroll
      for (int q = 0; q < 8; ++q) *(float4*)(d + 4 * q) = bq[q];
    }
  }
  __syncthreads();

  // ---- phase C: factor cols 32..63 among slots >= 32 ----
  factor32(sh, origin, ujjS + 32, redv, redk, 32, R, tid);

  // ---- consolidate B-cols (from LDS) + A-cols (global permute via LDS) ----
  #pragma unroll 1
  for (int t4 = 0; t4 < 4; ++t4) {
    int s = tid + (t4 << 8);
    if (s < R) {
      // B-cols: LDS -> consolidated row c0+s
      float* gb = A + (size_t)(c0 + s) * N + c0 + 32;
      const float* sp = &sh[s * 36];
      #pragma unroll
      for (int q = 0; q < 8; ++q) *(float4*)(gb + 4 * q) = *(const float4*)(sp + 4 * q);
      // A-cols: load source row origin[s] into (now free) LDS slot
      const float* ga = A + (size_t)origin[s] * N + c0;
      float* d = &sh[s * 36];
      #pragma unroll
      for (int q = 0; q < 8; ++q) *(float4*)(d + 4 * q) = *(const float4*)(ga + 4 * q);
    }
  }
  __syncthreads();   // all A-col reads done before any consolidated write
  #pragma unroll 1
  for (int t4 = 0; t4 < 4; ++t4) {
    int s = tid + (t4 << 8);
    if (s < R) {
      float* g = A + (size_t)(c0 + s) * N + c0;
      const float* sp = &sh[s * 36];
      #pragma unroll
      for (int q = 0; q < 8; ++q) *(float4*)(g + 4 * q) = *(const float4*)(sp + 4 * q);
    }
  }

  // ---- emit permutation: rowsrc[i] = physical row holding virtual row i ----
  for (int i = tid; i < R; i += 256) rowsrc[m * 1024 + i] = (unsigned short)origin[i];
  // ---- logsum: lane-parallel logs + shfl-reduce (wave 0) ----
  if (tid < 64) {
    double lg = log(fabs((double)ujjS[tid]));
    #pragma unroll
    for (int mask = 32; mask; mask >>= 1) lg += __shfl_xor(lg, mask);
    if (tid == 0) atomicAdd(&scores[m], lg);
  }
}

// ======================= permutation-gather + TRSM (width 64) =======================
// UNCHANGED from verified R7 kernel.
__global__ __launch_bounds__(256) void ptrsm_kernel(float* __restrict__ lu,
                                                    const unsigned short* __restrict__ rowsrc,
                                                    int c0, int ncs) {
  const int m  = blockIdx.x / ncs;
  const int cs = blockIdx.x % ncs;
  const int s0 = c0 + 64 + cs * 256;
  const int tid = threadIdx.x;
  const int col = s0 + tid;
  const bool ac = col < N;
  float* A = lu + (size_t)m * NN;
  const int R = N - c0;
  __shared__ int   rowAt[1024];     // content map over rows [c0, N)
  __shared__ float L11s[64][65];
  __shared__ int   dDst[80];
  __shared__ int   dSrc[80];
  __shared__ int   dcount;

  for (int r = tid; r < R; r += 256) rowAt[r] = (int)rowsrc[m * 1024 + r];
  if (tid == 0) dcount = 0;
  __syncthreads();
  // L11 from consolidated panel rows (written by panel_kernel)
  for (int idx = tid; idx < 4096; idx += 256) {
    int i = idx >> 6, k = idx & 63;
    L11s[i][k] = A[(size_t)(c0 + i) * N + c0 + k];
  }
  // collect displaced A22 rows (dst receives content of src); <= 64
  for (int r = 64 + tid; r < R; r += 256) {
    if (rowAt[r] != c0 + r) {
      int i = atomicAdd(&dcount, 1);
      dDst[i] = c0 + r; dSrc[i] = rowAt[r];
    }
  }
  __syncthreads();
  const int nd = dcount;   // <= 64

  // ---- read phase (all loads before any store) ----
  float pay[64];
  #pragma unroll
  for (int i = 0; i < 64; ++i)
    if (i < nd && ac) pay[i] = A[(size_t)dSrc[i] * N + col];
  float u[64];
  #pragma unroll
  for (int i = 0; i < 64; ++i)
    if (ac) u[i] = A[(size_t)rowAt[i] * N + col];

  // ---- TRSM: u = L11^{-1} a12 (unit diag) ----
  #pragma unroll
  for (int i = 1; i < 64; ++i) {
    float a = u[i];
    #pragma unroll
    for (int k = 0; k < 64; ++k)
      if (k < i) a -= L11s[i][k] * u[k];
    u[i] = a;
  }

  // ---- write phase ----
  #pragma unroll
  for (int i = 0; i < 64; ++i)
    if (i < nd && ac) A[(size_t)dDst[i] * N + col] = pay[i];
  #pragma unroll
  for (int i = 0; i < 64; ++i)
    if (ac) A[(size_t)(c0 + i) * N + col] = u[i];
}

// ======================= trailing update: A22 -= L21 @ U12 (K=64) ================
// UNCHANGED from verified R7 kernel.
__global__ __launch_bounds__(256) void update_kernel(float* __restrict__ lu,
                                                     int c0, int nrt, int ncs) {
  const int per = nrt * ncs;
  const int m  = blockIdx.x / per;
  const int t  = blockIdx.x % per;
  const int rt = t / ncs, cs = t % ncs;
  const int r0 = c0 + 64 + rt * 64;
  const int s0 = c0 + 64 + cs * 128;
  const int tid = threadIdx.x;
  float* A = lu + (size_t)m * NN;
  __shared__ float Lts[64][68];    // L21 tile transposed: [k][r]  (17.4 KB)
  __shared__ float Us[64][132];    // U12 stripe: [k][c]           (33.8 KB)
  for (int idx = tid; idx < 4096; idx += 256) {
    int r = idx >> 6, k = idx & 63;
    Lts[k][r] = (r0 + r < N) ? A[(size_t)(r0 + r) * N + c0 + k] : 0.0f;
  }
  for (int idx = tid; idx < 8192; idx += 256) {
    int k = idx >> 7, c = idx & 127;
    Us[k][c] = (s0 + c < N) ? A[(size_t)(c0 + k) * N + s0 + c] : 0.0f;
  }
  __syncthreads();
  const int tx = tid & 31;    // col group: 4 cols (128 total)
  const int ty = tid >> 5;    // row group: 8 rows (uniform a-reads per wave-half)
  float4 acc[8];
  #pragma unroll
  for (int e = 0; e < 8; ++e) acc[e] = make_float4(0.f, 0.f, 0.f, 0.f);
  #pragma unroll 4
  for (int k = 0; k < 64; ++k) {
    float4 b  = *(const float4*)&Us[k][tx * 4];
    float4 a0 = *(const float4*)&Lts[k][ty * 8 + 0];
    float4 a1 = *(const float4*)&Lts[k][ty * 8 + 4];
    acc[0].x += a0.x*b.x; acc[0].y += a0.x*b.y; acc[0].z += a0.x*b.z; acc[0].w += a0.x*b.w;
    acc[1].x += a0.y*b.x; acc[1].y += a0.y*b.y; acc[1].z += a0.y*b.z; acc[1].w += a0.y*b.w;
    acc[2].x += a0.z*b.x; acc[2].y += a0.z*b.y; acc[2].z += a0.z*b.z; acc[2].w += a0.z*b.w;
    acc[3].x += a0.w*b.x; acc[3].y += a0.w*b.y; acc[3].z += a0.w*b.z; acc[3].w += a0.w*b.w;
    acc[4].x += a1.x*b.x; acc[4].y += a1.x*b.y; acc[4].z += a1.x*b.z; acc[4].w += a1.x*b.w;
    acc[5].x += a1.y*b.x; acc[5].y += a1.y*b.y; acc[5].z += a1.y*b.z; acc[5].w += a1.y*b.w;
    acc[6].x += a1.z*b.x; acc[6].y += a1.z*b.y; acc[6].z += a1.z*b.z; acc[6].w += a1.z*b.w;
    acc[7].x += a1.w*b.x; acc[7].y += a1.w*b.y; acc[7].z += a1.w*b.z; acc[7].w += a1.w*b.w;
  }
  const bool colok = (s0 + tx * 4) < N;
  #pragma unroll
  for (int e = 0; e < 8; ++e) {
    int r = r0 + ty * 8 + e;
    if (r < N && colok) {
      float4* p = (float4*)&A[(size_t)r * N + s0 + tx * 4];
      float4 v = *p;
      v.x -= acc[e].x; v.y -= acc[e].y; v.z -= acc[e].z; v.w -= acc[e].w;
      *p = v;
    }
  }
}

// ======================= gate + top-k + effective weights =======================
__global__ void select_kernel(const void* __restrict__ flagsraw, const double* __restrict__ scores,
                              const float* __restrict__ w1, const float* __restrict__ b1,
                              const float* __restrict__ w2, const float* __restrict__ b2,
                              int* __restrict__ topidx, float* __restrict__ misc,
                              float* __restrict__ out_tail) {
  if (threadIdx.x != 0 || blockIdx.x != 0) return;
  const unsigned char* fb = (const unsigned char*)flagsraw;
  bool nonbin = false, off4 = false;
  for (int i = 0; i < 16; ++i) {
    if (fb[i] > 1) nonbin = true;
    if ((i & 3) && fb[i]) off4 = true;
  }
  int f[16]; int nact = 0;
  for (int i = 0; i < 16; ++i) {
    int v;
    if (nonbin)      v = (((const float*)flagsraw)[i] != 0.0f);
    else if (off4)   v = (fb[i] != 0);
    else             v = (((const int*)flagsraw)[i] != 0);
    f[i] = v; nact += v;
  }
  int gate = (nact >= 4) ? 1 : 0;   // THRESH = 4
  double sc[16];
  for (int i = 0; i < 16; ++i) sc[i] = f[i] ? scores[i] : -1.0e300;
  bool used[16] = {};
  for (int k = 0; k < 8; ++k) {     // descending, ties -> lowest index (lax.top_k)
    int bi = -1; double bv = 0.0;
    for (int i = 0; i < 16; ++i)
      if (!used[i] && (bi < 0 || sc[i] > bv)) { bv = sc[i]; bi = i; }
    used[bi] = true;
    topidx[k] = bi;
  }
  for (int cC = 0; cC < 10; ++cC) {
    float s = 0.0f;
    for (int h = 0; h < 32; ++h) s += w2[h] * w1[h * 10 + cC];
    misc[cC] = s;
  }
  float be = 0.0f;
  for (int h = 0; h < 32; ++h) be += w2[h] * b1[h];
  be += b2[0];
  misc[10] = be;
  ((int*)misc)[12] = gate;
  *out_tail = gate ? 1.0f : 0.0f;
}

// ======================= build combined right-hand matrices M0..M2 =======================
__global__ __launch_bounds__(256) void build_m_kernel(const float* __restrict__ x,
                                                      const int* __restrict__ topidx,
                                                      const float* __restrict__ misc,
                                                      float* __restrict__ M) {
  int i = blockIdx.x * 256 + threadIdx.x;   // 262144 float4 positions
  const float4* T1 = (const float4*)(x + (size_t)topidx[1] * NN);
  const float4* T2 = (const float4*)(x + (size_t)topidx[2] * NN);
  const float4* T3 = (const float4*)(x + (size_t)topidx[3] * NN);
  float w0 = misc[0], w1_ = misc[1], w2_ = misc[2], w3_ = misc[3], w4_ = misc[4], w5_ = misc[5];
  float4 t1 = T1[i], t2 = T2[i], t3 = T3[i];
  float4 m0, m1, m2;
  m0.x = w0 * t1.x + w1_ * t2.x + w2_ * t3.x;
  m0.y = w0 * t1.y + w1_ * t2.y + w2_ * t3.y;
  m0.z = w0 * t1.z + w1_ * t2.z + w2_ * t3.z;
  m0.w = w0 * t1.w + w1_ * t2.w + w2_ * t3.w;
  m1.x = w3_ * t2.x + w4_ * t3.x;
  m1.y = w3_ * t2.y + w4_ * t3.y;
  m1.z = w3_ * t2.z + w4_ * t3.z;
  m1.w = w3_ * t2.w + w4_ * t3.w;
  m2.x = w5_ * t3.x;  m2.y = w5_ * t3.y;  m2.z = w5_ * t3.z;  m2.w = w5_ * t3.w;
  ((float4*)M)[i] = m0;
  ((float4*)(M + NN))[i] = m1;
  ((float4*)(M + 2 * (size_t)NN))[i] = m2;
}

// ======================= split-K final GEMM: P[chunk] = A_chunk @ B_chunk ==========
__global__ __launch_bounds__(256) void final_gemm_kernel(const float* __restrict__ x,
                                                         const float* __restrict__ M,
                                                         const int* __restrict__ topidx,
                                                         float* __restrict__ P) {
  const int chunk = blockIdx.x >> 8;   // 0..5
  const int t  = blockIdx.x & 255;
  const int tr = t >> 4, tc = t & 15;
  const int mi  = chunk >> 1;
  const int k0b = (chunk & 1) << 9;    // 0 or 512
  const float* A = x + (size_t)topidx[mi] * NN;
  const float* B = M + (size_t)mi * NN;
  __shared__ float As[32][68];   // A^T fragment: As[k][r], float4-aligned stride
  __shared__ float Bs[32][68];
  const int ty = threadIdx.x >> 4, tx = threadIdx.x & 15;
  float acc[4][4] = {};
  for (int k0 = k0b; k0 < k0b + 512; k0 += 32) {
    for (int idx = threadIdx.x; idx < 2048; idx += 256) {
      int r = idx >> 5, k = idx & 31;
      As[k][r] = A[(size_t)(tr * 64 + r) * N + k0 + k];
    }
    for (int idx = threadIdx.x; idx < 2048; idx += 256) {
      int k = idx >> 6, cc = idx & 63;
      Bs[k][cc] = B[(size_t)(k0 + k) * N + tc * 64 + cc];
    }
    __syncthreads();
    #pragma unroll 8
    for (int k = 0; k < 32; ++k) {
      float4 a = *(const float4*)&As[k][ty * 4];
      float4 b = *(const float4*)&Bs[k][tx * 4];
      acc[0][0] += a.x * b.x; acc[0][1] += a.x * b.y; acc[0][2] += a.x * b.z; acc[0][3] += a.x * b.w;
      acc[1][0] += a.y * b.x; acc[1][1] += a.y * b.y; acc[1][2] += a.y * b.z; acc[1][3] += a.y * b.w;
      acc[2][0] += a.z * b.x; acc[2][1] += a.z * b.y; acc[2][2] += a.z * b.z; acc[2][3] += a.z * b.w;
      acc[3][0] += a.w * b.x; acc[3][1] += a.w * b.y; acc[3][2] += a.w * b.z; acc[3][3] += a.w * b.w;
    }
    __syncthreads();
  }
  float* Pc = P + (size_t)chunk * NN;
  #pragma unroll
  for (int i = 0; i < 4; ++i) {
    size_t r = (size_t)(tr * 64 + ty * 4 + i);
    float4 v = make_float4(acc[i][0], acc[i][1], acc[i][2], acc[i][3]);
    *(float4*)&Pc[r * N + tc * 64 + tx * 4] = v;
  }
}

// ======================= reduce partials + preserve channels + bias ================
__global__ __launch_bounds__(256) void reduce_out_kernel(const float* __restrict__ x,
                                                         const float* __restrict__ P,
                                                         const int* __restrict__ topidx,
                                                         const float* __restrict__ misc,
                                                         float* __restrict__ out) {
  int i = blockIdx.x * 256 + threadIdx.x;   // 262144 float4 positions
  int gate = ((const int*)misc)[12];
  float4* o = (float4*)out;
  if (!gate) { o[i] = make_float4(0.f, 0.f, 0.f, 0.f); return; }
  float w6 = misc[6], w7 = misc[7], w8 = misc[8], w9 = misc[9], be = misc[10];
  float4 p0 = ((const float4*)(x + (size_t)topidx[4] * NN))[i];
  float4 p1 = ((const float4*)(x + (size_t)topidx[5] * NN))[i];
  float4 p2 = ((const float4*)(x + (size_t)topidx[6] * NN))[i];
  float4 p3 = ((const float4*)(x + (size_t)topidx[7] * NN))[i];
  float4 r;
  r.x = be + w6 * p0.x + w7 * p1.x + w8 * p2.x + w9 * p3.x;
  r.y = be + w6 * p0.y + w7 * p1.y + w8 * p2.y + w9 * p3.y;
  r.z = be + w6 * p0.z + w7 * p1.z + w8 * p2.z + w9 * p3.z;
  r.w = be + w6 * p0.w + w7 * p1.w + w8 * p2.w + w9 * p3.w;
  #pragma unroll
  for (int cN = 0; cN < 6; ++cN) {
    float4 q = ((const float4*)(P + (size_t)cN * NN))[i];
    r.x += q.x; r.y += q.y; r.z += q.z; r.w += q.w;
  }
  o[i] = r;
}

// ======================= host =======================
extern "C" void kernel_launch(void* const* d_in, const int* in_sizes, int n_in,
                              void* d_out, int out_size, void* d_ws, size_t ws_size,
                              hipStream_t stream) {
  const float* x  = (const float*)d_in[0];
  const void*  fl = d_in[1];
  const float* w1 = (const float*)d_in[2];
  const float* b1 = (const float*)d_in[3];
  const float* w2 = (const float*)d_in[4];
  const float* b2 = (const float*)d_in[5];
  float* out = (float*)d_out;

  char* ws = (char*)d_ws;
  float* LU = (float*)ws;                                // 64 MB (dead after LU phase)
  float* Mm = (float*)ws;                                // 12 MB, reuses LU space
  float* P  = (float*)(ws + (size_t)12 * 1024 * 1024);   // 24 MB partials, inside old LU
  size_t tail = (size_t)16 * NN * sizeof(float);         // 67,108,864
  double* scores = (double*)(ws + tail);                 // 16 doubles
  unsigned short* rowsrc = (unsigned short*)(ws + tail + 256);     // 16*1024 u16 = 32 KB
  int*    topidx = (int*)(ws + tail + 256 + 32768);      // 8 ints
  float*  misc   = (float*)(ws + tail + 256 + 32768 + 256); // weff[10], beff, gate

  init_kernel<<<1, 64, 0, stream>>>(scores);
  copy_kernel<<<16384, 256, 0, stream>>>((const float4*)x, (float4*)LU);

  for (int c0 = 0; c0 < N; c0 += 64) {
    panel_kernel<<<16, 256, 0, stream>>>(LU, rowsrc, scores, c0);
    int tcols = N - c0 - 64;
    if (tcols > 0) {
      int ncs = (tcols + 255) / 256;
      ptrsm_kernel<<<16 * ncs, 256, 0, stream>>>(LU, rowsrc, c0, ncs);
      int nrt = (tcols + 63) / 64;
      int ncs2 = (tcols + 127) / 128;
      update_kernel<<<16 * nrt * ncs2, 256, 0, stream>>>(LU, c0, nrt, ncs2);
    }
  }

  select_kernel<<<1, 64, 0, stream>>>(fl, scores, w1, b1, w2, b2, topidx, misc, out + NN);
  build_m_kernel<<<1024, 256, 0, stream>>>(x, topidx, misc, Mm);
  final_gemm_kernel<<<1536, 256, 0, stream>>>(x, Mm, topidx, P);
  reduce_out_kernel<<<1024, 256, 0, stream>>>(x, P, topidx, misc, out);
}